// Round 2
// baseline (6653.391 us; speedup 1.0000x reference)
//
#include <hip/hip_runtime.h>
#include <cstdint>
#include <cstddef>

// ---------------------------------------------------------------------------
// Round 1: correct fp32 baseline, batch-chunked to fit unknown ws_size.
// Per batch chunk of Bc rows (MC = Bc*T):
//   1) xw0[dir] = X^T-fused GEMM (MC x 512, K=271) + b_ih + b_hh   (2 launches)
//   2) lstm_rec layer0 (both dirs, 2*Bc blocks, w_hh in VGPRs)     -> h0c
//   3) xw1[dir] = h0c GEMM (K=256)                                 (2 launches)
//   4) lstm_rec layer1                                             -> h1c
//   5) u = tanh(h1c @ att_W)   (reuses xw buffer)
//   6) a[m] = u[m] . att_v
//   7) per-batch softmax over T + pooling -> wgt[ch slice]
// After all chunks: out = wgt @ head_W^T + head_b.
// ws floats: wgt[512*256] | xw[2*MC*512] | h0c[MC*256] | h1c[MC*256] | a[MC]
// bytes(Bc) = 4*(131072 + Bc*281*1537): Bc=128 -> 221MB ... Bc=8 -> 14MB.
// Bc chosen largest fitting ws_size (deterministic across calls).
// ---------------------------------------------------------------------------

constexpr int Bn   = 512;
constexpr int Cn   = 271;
constexpr int Tn   = 281;
constexpr int Hn   = 128;
constexpr int NCLS = 1854;
constexpr int Gn   = 4 * Hn;    // 512

#define DEVINL __device__ __forceinline__

DEVINL float sigm(float x) { return 1.f / (1.f + __expf(-x)); }

// ---------------------------------------------------------------------------
// Generic fp32 tiled GEMM: C[m][n] = act( sum_k A(m,k)*B(k,n) + bias1 + bias2 )
// Tile 128(M) x 64(N), K-chunks of 8, 256 threads, 8x4 acc/thread.
// AMODE 0: A row-major [M][K], K%4==0.  AMODE 1: A(m,k)=X[(m/T)*C*T + k*T + m%T].
// BMODE 0: B [N][K] (A@B^T).            BMODE 1: B [K][N].
// ACT 1: tanh. NBIAS: number of bias vectors.
// ---------------------------------------------------------------------------
template <int AMODE, int BMODE, int ACT, int NBIAS>
__global__ __launch_bounds__(256) void gemm_tile(
    const float* __restrict__ A, const float* __restrict__ Bm,
    const float* __restrict__ bias1, const float* __restrict__ bias2,
    float* __restrict__ Cout, int Mdim, int Ndim, int Kdim, int ldc)
{
  __shared__ __align__(16) float As[8][128];
  __shared__ __align__(16) float Bs[8][64];

  const int tid  = threadIdx.x;
  const int tx   = tid & 15;
  const int ty   = tid >> 4;
  const int row0 = blockIdx.x * 128;
  const int col0 = blockIdx.y * 64;

  float acc[8][4];
#pragma unroll
  for (int i = 0; i < 8; i++)
#pragma unroll
    for (int j = 0; j < 4; j++) acc[i][j] = 0.f;

  for (int k0 = 0; k0 < Kdim; k0 += 8) {
    if (AMODE == 0) {
      const int q  = tid >> 7;
      const int r  = tid & 127;
      const int gr = row0 + r;
      const int gk = k0 + q * 4;
      float4 v = make_float4(0.f, 0.f, 0.f, 0.f);
      if (gr < Mdim && gk + 3 < Kdim)
        v = *(const float4*)&A[(size_t)gr * Kdim + gk];
      As[q * 4 + 0][r] = v.x;
      As[q * 4 + 1][r] = v.y;
      As[q * 4 + 2][r] = v.z;
      As[q * 4 + 3][r] = v.w;
    } else {
#pragma unroll
      for (int l = 0; l < 4; l++) {
        const int e  = tid + l * 256;
        const int r  = e & 127;
        const int kk = e >> 7;
        const int gr = row0 + r;
        const int gk = k0 + kk;
        float v = 0.f;
        if (gr < Mdim && gk < Kdim) {
          const int bb = gr / Tn;
          const int tt = gr - bb * Tn;
          v = A[((size_t)bb * Cn + gk) * Tn + tt];  // coalesced over tt
        }
        As[kk][r] = v;
      }
    }
#pragma unroll
    for (int l = 0; l < 2; l++) {
      const int e = tid + l * 256;
      int kk, cc;
      if (BMODE == 0) { kk = e & 7;  cc = e >> 3; }
      else            { cc = e & 63; kk = e >> 6; }
      const int gn = col0 + cc;
      const int gk = k0 + kk;
      float v = 0.f;
      if (gn < Ndim && gk < Kdim)
        v = (BMODE == 0) ? Bm[(size_t)gn * Kdim + gk]
                         : Bm[(size_t)gk * Ndim + gn];
      Bs[kk][cc] = v;
    }
    __syncthreads();
#pragma unroll
    for (int kk = 0; kk < 8; kk++) {
      const float4 a0 = *(const float4*)&As[kk][ty * 8];
      const float4 a1 = *(const float4*)&As[kk][ty * 8 + 4];
      const float4 b0 = *(const float4*)&Bs[kk][tx * 4];
      const float av[8] = {a0.x, a0.y, a0.z, a0.w, a1.x, a1.y, a1.z, a1.w};
      const float bv[4] = {b0.x, b0.y, b0.z, b0.w};
#pragma unroll
      for (int i = 0; i < 8; i++)
#pragma unroll
        for (int j = 0; j < 4; j++) acc[i][j] = fmaf(av[i], bv[j], acc[i][j]);
    }
    __syncthreads();
  }
#pragma unroll
  for (int i = 0; i < 8; i++) {
    const int gr = row0 + ty * 8 + i;
    if (gr >= Mdim) continue;
    const size_t rowoff = (size_t)gr * ldc;
#pragma unroll
    for (int j = 0; j < 4; j++) {
      const int gn = col0 + tx * 4 + j;
      if (gn >= Ndim) continue;
      float v = acc[i][j];
      if (NBIAS >= 1) v += bias1[gn];
      if (NBIAS >= 2) v += bias2[gn];
      if (ACT == 1) v = tanhf(v);
      Cout[rowoff + gn] = v;
    }
  }
}

// ---------------------------------------------------------------------------
// LSTM recurrence, chunk-local. grid (Bc/R, 2), block 512. Thread n owns
// gate-row n of w_hh (128 fp32 in VGPRs). R batch rows per block.
// xw: [2][MC][512] chunk-local (includes b_ih + b_hh). hout: [MC][256].
// ---------------------------------------------------------------------------
template <int R>
__global__ __launch_bounds__(512, 2) void lstm_rec(
    const float* __restrict__ xw,
    const float* __restrict__ whhf,
    const float* __restrict__ whhb,
    float* __restrict__ hout, int MC)
{
  const int dir = blockIdx.y;
  const int r0  = blockIdx.x * R;
  const int tid = threadIdx.x;
  const float* __restrict__ whh = dir ? whhb : whhf;
  const float* __restrict__ xwd = xw + (size_t)dir * MC * Gn;

  __shared__ __align__(16) float hl[R][Hn];
  __shared__ __align__(16) float gl[R][Gn];

  float w[128];
  {
    const float4* wr = (const float4*)(whh + (size_t)tid * Hn);
#pragma unroll
    for (int q = 0; q < 32; q++) {
      const float4 t4 = wr[q];
      w[4 * q + 0] = t4.x; w[4 * q + 1] = t4.y;
      w[4 * q + 2] = t4.z; w[4 * q + 3] = t4.w;
    }
  }
  const int biu = tid >> 7;
  const int ju  = tid & 127;
  if (biu < R) hl[biu][ju] = 0.f;
  float c = 0.f;
  __syncthreads();

  for (int s = 0; s < Tn; s++) {
    const int t = dir ? (Tn - 1 - s) : s;
    float xg[R];
#pragma unroll
    for (int bi = 0; bi < R; bi++)
      xg[bi] = xwd[((size_t)(r0 + bi) * Tn + t) * Gn + tid];
    float a0[R], a1[R];
#pragma unroll
    for (int bi = 0; bi < R; bi++) { a0[bi] = 0.f; a1[bi] = 0.f; }
#pragma unroll
    for (int q = 0; q < 16; q++) {
#pragma unroll
      for (int bi = 0; bi < R; bi++) {
        const float4 hA = *(const float4*)&hl[bi][8 * q];
        const float4 hB = *(const float4*)&hl[bi][8 * q + 4];
        a0[bi] = fmaf(w[8 * q + 0], hA.x, a0[bi]);
        a0[bi] = fmaf(w[8 * q + 1], hA.y, a0[bi]);
        a0[bi] = fmaf(w[8 * q + 2], hA.z, a0[bi]);
        a0[bi] = fmaf(w[8 * q + 3], hA.w, a0[bi]);
        a1[bi] = fmaf(w[8 * q + 4], hB.x, a1[bi]);
        a1[bi] = fmaf(w[8 * q + 5], hB.y, a1[bi]);
        a1[bi] = fmaf(w[8 * q + 6], hB.z, a1[bi]);
        a1[bi] = fmaf(w[8 * q + 7], hB.w, a1[bi]);
      }
    }
#pragma unroll
    for (int bi = 0; bi < R; bi++) gl[bi][tid] = a0[bi] + a1[bi] + xg[bi];
    __syncthreads();
    if (biu < R) {
      const float gi = gl[biu][ju];
      const float gf = gl[biu][Hn + ju];
      const float gg = gl[biu][2 * Hn + ju];
      const float go = gl[biu][3 * Hn + ju];
      const float iv = sigm(gi), fv = sigm(gf), ov = sigm(go);
      const float gv = tanhf(gg);
      c = fv * c + iv * gv;
      const float hv = ov * tanhf(c);
      hl[biu][ju] = hv;
      hout[((size_t)(r0 + biu) * Tn + t) * 256 + dir * Hn + ju] = hv;
    }
    __syncthreads();
  }
}

// ---------------------------------------------------------------------------
// a[m] = u[m][0:256] . v[0:256] — one wave per row.
// ---------------------------------------------------------------------------
__global__ __launch_bounds__(256) void dot_v_kernel(
    const float* __restrict__ u, const float* __restrict__ v,
    float* __restrict__ a, int MC)
{
  const int lane = threadIdx.x & 63;
  const int row  = blockIdx.x * 4 + (threadIdx.x >> 6);
  if (row >= MC) return;
  const float4 uv = ((const float4*)(u + (size_t)row * 256))[lane];
  const float4 vv = ((const float4*)v)[lane];
  float p = uv.x * vv.x + uv.y * vv.y + uv.z * vv.z + uv.w * vv.w;
#pragma unroll
  for (int off = 32; off > 0; off >>= 1) p += __shfl_down(p, off);
  if (lane == 0) a[row] = p;
}

// ---------------------------------------------------------------------------
// softmax over T + pooling: wout[b_local][j] = sum_t softmax(a[b_local])[t]*h1[b_local][t][j]
// grid = Bc, block = 256. All pointers chunk-local.
// ---------------------------------------------------------------------------
__global__ __launch_bounds__(256) void attn_pool(
    const float* __restrict__ a, const float* __restrict__ h1,
    float* __restrict__ wout)
{
  const int b    = blockIdx.x;
  const int tid  = threadIdx.x;
  const int lane = tid & 63;
  const int wid  = tid >> 6;
  __shared__ float sa[Tn];
  __shared__ float red[8];

  float lmax = -3.4e38f;
  for (int t = tid; t < Tn; t += 256) {
    const float x = a[(size_t)b * Tn + t];
    sa[t] = x;
    lmax  = fmaxf(lmax, x);
  }
#pragma unroll
  for (int off = 1; off < 64; off <<= 1) lmax = fmaxf(lmax, __shfl_xor(lmax, off));
  if (lane == 0) red[wid] = lmax;
  __syncthreads();
  const float bmax = fmaxf(fmaxf(red[0], red[1]), fmaxf(red[2], red[3]));

  float lsum = 0.f;
  for (int t = tid; t < Tn; t += 256) {
    const float e = __expf(sa[t] - bmax);
    sa[t] = e;
    lsum += e;
  }
#pragma unroll
  for (int off = 1; off < 64; off <<= 1) lsum += __shfl_xor(lsum, off);
  if (lane == 0) red[4 + wid] = lsum;
  __syncthreads();
  const float inv = 1.f / (red[4] + red[5] + red[6] + red[7]);

  float acc = 0.f;
  const float* hb = h1 + (size_t)b * Tn * 256 + tid;
  for (int t = 0; t < Tn; t++) acc += sa[t] * hb[(size_t)t * 256];
  wout[(size_t)b * 256 + tid] = acc * inv;
}

// ---------------------------------------------------------------------------
extern "C" void kernel_launch(void* const* d_in, const int* in_sizes, int n_in,
                              void* d_out, int out_size, void* d_ws, size_t ws_size,
                              hipStream_t stream)
{
  const float* X      = (const float*)d_in[0];
  const float* w_ih0f = (const float*)d_in[1];
  const float* w_hh0f = (const float*)d_in[2];
  const float* b_ih0f = (const float*)d_in[3];
  const float* b_hh0f = (const float*)d_in[4];
  const float* w_ih0b = (const float*)d_in[5];
  const float* w_hh0b = (const float*)d_in[6];
  const float* b_ih0b = (const float*)d_in[7];
  const float* b_hh0b = (const float*)d_in[8];
  const float* w_ih1f = (const float*)d_in[9];
  const float* w_hh1f = (const float*)d_in[10];
  const float* b_ih1f = (const float*)d_in[11];
  const float* b_hh1f = (const float*)d_in[12];
  const float* w_ih1b = (const float*)d_in[13];
  const float* w_hh1b = (const float*)d_in[14];
  const float* b_ih1b = (const float*)d_in[15];
  const float* b_hh1b = (const float*)d_in[16];
  const float* att_W  = (const float*)d_in[17];
  const float* att_v  = (const float*)d_in[18];
  const float* head_W = (const float*)d_in[19];
  const float* head_b = (const float*)d_in[20];

  // pick largest chunk size fitting ws_size (deterministic across calls)
  int Bc = 8;
  {
    const int cands[5] = {128, 64, 32, 16, 8};
    for (int i = 0; i < 5; i++) {
      const size_t mc   = (size_t)cands[i] * Tn;
      const size_t need = 4ull * ((size_t)512 * 256 + mc * 1537);
      if (need <= ws_size) { Bc = cands[i]; break; }
    }
  }
  const size_t MCs = (size_t)Bc * Tn;
  const int    MC  = (int)MCs;

  float* wgt = (float*)d_ws;               // [512][256] persistent
  float* xwc = wgt + (size_t)512 * 256;    // [2][MC][512]
  float* h0c = xwc + 2 * MCs * Gn;         // [MC][256]
  float* h1c = h0c + MCs * 256;            // [MC][256]
  float* ac  = h1c + MCs * 256;            // [MC]
  float* u   = xwc;                        // reuse (xw dead by phase 5)

  const dim3 blk(256);
  const int  mt = (MC + 127) / 128;
  const dim3 gXW(mt, Gn / 64);             // (., 8)
  const dim3 gU(mt, 256 / 64);             // (., 4)
  const int  nch = Bn / Bc;

  for (int ch = 0; ch < nch; ch++) {
    const float* Xc   = X + (size_t)ch * Bc * Cn * Tn;
    float*       wgtc = wgt + (size_t)ch * Bc * 256;

    // 1) layer-0 input projections (transpose fused), both biases folded
    gemm_tile<1, 0, 0, 2><<<gXW, blk, 0, stream>>>(Xc, w_ih0f, b_ih0f, b_hh0f,
                                                   xwc, MC, Gn, Cn, Gn);
    gemm_tile<1, 0, 0, 2><<<gXW, blk, 0, stream>>>(Xc, w_ih0b, b_ih0b, b_hh0b,
                                                   xwc + MCs * Gn, MC, Gn, Cn, Gn);
    // 2) layer-0 recurrence
    lstm_rec<1><<<dim3(Bc, 2), dim3(512), 0, stream>>>(xwc, w_hh0f, w_hh0b, h0c, MC);
    // 3) layer-1 input projections
    gemm_tile<0, 0, 0, 2><<<gXW, blk, 0, stream>>>(h0c, w_ih1f, b_ih1f, b_hh1f,
                                                   xwc, MC, Gn, 256, Gn);
    gemm_tile<0, 0, 0, 2><<<gXW, blk, 0, stream>>>(h0c, w_ih1b, b_ih1b, b_hh1b,
                                                   xwc + MCs * Gn, MC, Gn, 256, Gn);
    // 4) layer-1 recurrence
    lstm_rec<1><<<dim3(Bc, 2), dim3(512), 0, stream>>>(xwc, w_hh1f, w_hh1b, h1c, MC);
    // 5) u = tanh(h1 @ att_W)
    gemm_tile<0, 1, 1, 0><<<gU, blk, 0, stream>>>(h1c, att_W, nullptr, nullptr,
                                                  u, MC, 256, 256, 256);
    // 6) a = u . att_v
    dot_v_kernel<<<dim3((MC + 3) / 4), blk, 0, stream>>>(u, att_v, ac, MC);
    // 7) softmax + pooling into this chunk's wgt slice
    attn_pool<<<dim3(Bc), blk, 0, stream>>>(ac, h1c, wgtc);
  }
  // 8) head
  gemm_tile<0, 0, 0, 1><<<dim3((Bn + 127) / 128, (NCLS + 63) / 64), blk, 0, stream>>>(
      wgt, head_W, head_b, nullptr, (float*)d_out, Bn, NCLS, 256, NCLS);
}